// Round 3
// baseline (755.197 us; speedup 1.0000x reference)
//
#include <hip/hip_runtime.h>
#include <cstddef>
#include <cstdint>

// ---------------- problem constants ----------------
#define ALPHA_C 7.7550531393693407f   // -log(0.001/7*3)
constexpr int BB = 2;      // batch
constexpr int LL = 2048;   // seq len
constexpr int DD = 512;    // d_model
constexpr int HH = 8;      // heads
constexpr size_t OUT0     = (size_t)BB * LL * DD;        // output 0 floats
constexpr size_t QH_ELEMS = (size_t)BB * HH * LL * 64;   // per-projection floats

typedef __attribute__((ext_vector_type(8))) short bf16x8;
typedef __attribute__((ext_vector_type(4))) short short4v;
typedef __attribute__((ext_vector_type(4))) float f32x4;

__device__ inline short f2bf(float x) {
  union { float f; unsigned u; } un; un.f = x;
  unsigned r = un.u + 0x7fffu + ((un.u >> 16) & 1u);   // RNE
  return (short)(r >> 16);
}
__device__ inline float bf2f(short s) {
  union { unsigned u; float f; } un; un.u = ((unsigned)(unsigned short)s) << 16;
  return un.f;
}
// 3-way bf16 split: x ~= h + m + l (~24 mantissa bits)
__device__ inline void split3(float x, short& h, short& m, short& l) {
  h = f2bf(x); float r = x - bf2f(h);
  m = f2bf(r); float r2 = r - bf2f(m);
  l = f2bf(r2);
}

// ---------------- K1: fused QKV projection (fp32 SGEMM) ----------------
// grid (24, 64). For sel==2 (V) the epilogue writes bf16 TRANSPOSED vt[bh][d][l].
__global__ __launch_bounds__(256) void k_proj(
    const float* __restrict__ q, const float* __restrict__ k, const float* __restrict__ v,
    const float* __restrict__ wq, const float* __restrict__ wk, const float* __restrict__ wv,
    float* __restrict__ qh, float* __restrict__ kh, short* __restrict__ vt)
{
  const int bx  = blockIdx.x;
  const int sel = bx >> 3;                 // 0=q,1=k,2=v
  const int n0  = (bx & 7) * 64;
  const int m0  = blockIdx.y * 64;
  const float* X = sel == 0 ? q  : (sel == 1 ? k  : v);
  const float* W = sel == 0 ? wq : (sel == 1 ? wk : wv);

  __shared__ float As[32][68];
  __shared__ float Bs[32][68];
  const int tid = threadIdx.x;
  const int tr = tid >> 4, tc = tid & 15;
  const int lm = tid >> 2, lk0 = tid & 3;

  float acc[4][4] = {};
  for (int k0 = 0; k0 < 512; k0 += 32) {
    #pragma unroll
    for (int it = 0; it < 2; ++it) {
      int kv = lk0 + 4 * it;
      float4 a = *(const float4*)&X[(size_t)(m0 + lm) * 512 + k0 + kv * 4];
      As[kv*4+0][lm] = a.x; As[kv*4+1][lm] = a.y; As[kv*4+2][lm] = a.z; As[kv*4+3][lm] = a.w;
      float4 b = *(const float4*)&W[(size_t)(n0 + lm) * 512 + k0 + kv * 4];
      Bs[kv*4+0][lm] = b.x; Bs[kv*4+1][lm] = b.y; Bs[kv*4+2][lm] = b.z; Bs[kv*4+3][lm] = b.w;
    }
    __syncthreads();
    #pragma unroll 8
    for (int kk = 0; kk < 32; ++kk) {
      float4 av = *(const float4*)&As[kk][tr * 4];
      float4 bv = *(const float4*)&Bs[kk][tc * 4];
      acc[0][0] += av.x*bv.x; acc[0][1] += av.x*bv.y; acc[0][2] += av.x*bv.z; acc[0][3] += av.x*bv.w;
      acc[1][0] += av.y*bv.x; acc[1][1] += av.y*bv.y; acc[1][2] += av.y*bv.z; acc[1][3] += av.y*bv.w;
      acc[2][0] += av.z*bv.x; acc[2][1] += av.z*bv.y; acc[2][2] += av.z*bv.z; acc[2][3] += av.z*bv.w;
      acc[3][0] += av.w*bv.x; acc[3][1] += av.w*bv.y; acc[3][2] += av.w*bv.z; acc[3][3] += av.w*bv.w;
    }
    __syncthreads();
  }

  if (sel < 2) {
    float* Y = sel == 0 ? qh : kh;
    const int e = n0 + tc * 4;
    const int h = e >> 6, dk = e & 63;
    #pragma unroll
    for (int r = 0; r < 4; ++r) {
      int m = m0 + tr * 4 + r;
      int b = m >> 11, l = m & 2047;
      float4 o; o.x = acc[r][0]; o.y = acc[r][1]; o.z = acc[r][2]; o.w = acc[r][3];
      *(float4*)&Y[((size_t)(b * HH + h) * LL + l) * 64 + dk] = o;
    }
  } else {
    const int b  = m0 >> 11;
    const int l0 = (m0 & 2047) + tr * 4;   // 4 consecutive l values
    #pragma unroll
    for (int c = 0; c < 4; ++c) {
      int e = n0 + tc * 4 + c, h = e >> 6, dk = e & 63;
      short4v s;
      s[0] = f2bf(acc[0][c]); s[1] = f2bf(acc[1][c]);
      s[2] = f2bf(acc[2][c]); s[3] = f2bf(acc[3][c]);
      *(short4v*)&vt[(((size_t)b * HH + h) * 64 + dk) * LL + l0] = s;
    }
  }
}

// ---------------- K2: logits via 3-way-bf16-split MFMA + per-tile softmax stats ------
// grid (32 jt, 32 it, 16 bh). Stride-72 LDS (conflict-free MFMA reads), column-major
// staging (conflict-free stores, coalesced scalar global loads).
__global__ __launch_bounds__(256) void k_qk(
    const float* __restrict__ qh, const float* __restrict__ kh,
    float* __restrict__ eldout, float* __restrict__ stats)
{
  const int j0 = blockIdx.x * 64;
  const int i0 = blockIdx.y * 64;
  const int jt = blockIdx.x;
  const int bh = blockIdx.z;
  const float* Qb = qh + (size_t)bh * LL * 64;
  const float* Kb = kh + (size_t)bh * LL * 64;
  float*       Ob = eldout + (size_t)bh * LL * LL;

  __shared__ short Ah[64*72], Am[64*72], Al[64*72];
  __shared__ short Bh[64*72], Bm[64*72], Bl[64*72];

  const int tid = threadIdx.x;
  const int lane = tid & 63, w = tid >> 6;

  // stage: lane = k-column, 4 rows per pass
  const int sr = tid >> 6, sc = tid & 63;
  #pragma unroll
  for (int it = 0; it < 16; ++it) {
    int r = it * 4 + sr;
    {
      float a = Qb[(size_t)(i0 + r) * 64 + sc];
      short h, m, l; split3(a, h, m, l);
      Ah[r*72+sc] = h; Am[r*72+sc] = m; Al[r*72+sc] = l;
    }
    {
      float b = Kb[(size_t)(j0 + r) * 64 + sc];
      short h, m, l; split3(b, h, m, l);
      Bh[r*72+sc] = h; Bm[r*72+sc] = m; Bl[r*72+sc] = l;
    }
  }
  __syncthreads();

  f32x4 acc[4];
  #pragma unroll
  for (int t = 0; t < 4; ++t) { acc[t][0]=0.f; acc[t][1]=0.f; acc[t][2]=0.f; acc[t][3]=0.f; }

  #pragma unroll
  for (int ch = 0; ch < 2; ++ch) {
    const int ka = ((lane >> 4) << 3) + ch * 32;
    const int ar = (w * 16 + (lane & 15)) * 72 + ka;
    bf16x8 ah = *(const bf16x8*)&Ah[ar];
    bf16x8 am = *(const bf16x8*)&Am[ar];
    bf16x8 al = *(const bf16x8*)&Al[ar];
    #pragma unroll
    for (int t = 0; t < 4; ++t) {
      const int br = (t * 16 + (lane & 15)) * 72 + ka;
      bf16x8 bh_ = *(const bf16x8*)&Bh[br];
      bf16x8 bm_ = *(const bf16x8*)&Bm[br];
      bf16x8 bl_ = *(const bf16x8*)&Bl[br];
      acc[t] = __builtin_amdgcn_mfma_f32_16x16x32_bf16(ah, bh_, acc[t], 0, 0, 0);
      acc[t] = __builtin_amdgcn_mfma_f32_16x16x32_bf16(ah, bm_, acc[t], 0, 0, 0);
      acc[t] = __builtin_amdgcn_mfma_f32_16x16x32_bf16(am, bh_, acc[t], 0, 0, 0);
      acc[t] = __builtin_amdgcn_mfma_f32_16x16x32_bf16(ah, bl_, acc[t], 0, 0, 0);
      acc[t] = __builtin_amdgcn_mfma_f32_16x16x32_bf16(al, bh_, acc[t], 0, 0, 0);
      acc[t] = __builtin_amdgcn_mfma_f32_16x16x32_bf16(am, bm_, acc[t], 0, 0, 0);
    }
  }

  // epilogue: eld, store, per-tile (max, sumexp)
  const int quad = lane >> 4, colg = lane & 15;
  float eld[4][4];
  #pragma unroll
  for (int t = 0; t < 4; ++t)
    #pragma unroll
    for (int r = 0; r < 4; ++r) {
      int i = i0 + w * 16 + quad * 4 + r;
      int j = j0 + t * 16 + colg;
      float e = -ALPHA_C * (float)(j - i) * (acc[t][r] * 0.125f);
      eld[t][r] = e;
      Ob[(size_t)i * LL + j] = e;
    }
  #pragma unroll
  for (int r = 0; r < 4; ++r) {
    float mx = fmaxf(fmaxf(eld[0][r], eld[1][r]), fmaxf(eld[2][r], eld[3][r]));
    #pragma unroll
    for (int d = 1; d < 16; d <<= 1) mx = fmaxf(mx, __shfl_xor(mx, d));
    float s = __expf(eld[0][r]-mx) + __expf(eld[1][r]-mx) + __expf(eld[2][r]-mx) + __expf(eld[3][r]-mx);
    #pragma unroll
    for (int d = 1; d < 16; d <<= 1) s += __shfl_xor(s, d);
    if (colg == 0) {
      int i = i0 + w * 16 + quad * 4 + r;
      size_t idx = (((size_t)bh * LL + i) * 32 + jt) * 2;
      stats[idx] = mx; stats[idx + 1] = s;
    }
  }
}

// ---------------- K3: per-row reduce of tile stats -> (M, S) ----------------
__global__ __launch_bounds__(256) void k_rowstats(
    const float* __restrict__ stats, float* __restrict__ rowstats)
{
  const int row = blockIdx.x * 256 + threadIdx.x;   // < 32768
  const float* S = stats + (size_t)row * 64;
  float M = -3.0e38f, Ss = 0.f;
  #pragma unroll 8
  for (int k = 0; k < 32; ++k) {
    float m = S[2*k], s = S[2*k+1];
    float nM = fmaxf(M, m);
    Ss = Ss * __expf(M - nM) + s * __expf(m - nM);
    M = nM;
  }
  rowstats[(size_t)row * 2]     = M;
  rowstats[(size_t)row * 2 + 1] = Ss;
}

// ---------------- K4: softmax + pool (in place) + PV (bf16 MFMA), fused --------
// grid (64 i-tiles of 32 rows, 16 bh), 256 thr. lane = column everywhere;
// stride-72 MFMA tiles; V pre-transposed bf16 (vt) so staging is a straight copy.
__global__ __launch_bounds__(256) void k_sm_pool_pv(
    float* __restrict__ Pg_all, const float* __restrict__ rowstats,
    const short* __restrict__ vt, float* __restrict__ outh)
{
  const int i0 = blockIdx.x * 32;
  const int bh = blockIdx.y;
  const int b = bh >> 3, h = bh & 7;
  float*       Pg = Pg_all + (size_t)bh * LL * LL;
  const short* Vt = vt + (size_t)bh * 64 * LL;

  __shared__ float pL[32][66];       // [row][0]=left halo, [1..64]=tile, [65]=right halo
  __shared__ float Mrow[32], invS[32], lhalo[32];
  __shared__ short Asm[32 * 72];     // pooled bf16, A[m=i][k=j], stride 72
  __shared__ short Vsm[64 * 72];     // V^T bf16, B[n=d][k=j], stride 72

  const int tid = threadIdx.x;
  const int lane = tid & 63, w = tid >> 6;
  const int wr = w & 1, wd = w >> 1;
  const int col = lane;              // lane = column

  if (tid < 32) {
    float2 ms = *(const float2*)&rowstats[((size_t)bh * LL + i0 + tid) * 2];
    Mrow[tid] = ms.x; invS[tid] = 1.0f / ms.y; lhalo[tid] = 0.f;
  }
  __syncthreads();

  // per-thread copies of the 8 row-stats this wave owns
  float Mr[8], iSr[8];
  #pragma unroll
  for (int rr = 0; rr < 8; ++rr) { Mr[rr] = Mrow[8*w+rr]; iSr[rr] = invS[8*w+rr]; }

  f32x4 acc[2];
  acc[0][0]=0.f;acc[0][1]=0.f;acc[0][2]=0.f;acc[0][3]=0.f;
  acc[1][0]=0.f;acc[1][1]=0.f;acc[1][2]=0.f;acc[1][3]=0.f;

  const int vd = tid >> 2, vq = tid & 3;   // V staging: 64 rows x 4 chunks of 32B

  for (int j0 = 0; j0 < LL; j0 += 64) {
    // phase 1: logits -> probabilities into pL (lane=col, conflict-free), halos, V copy
    #pragma unroll
    for (int rr = 0; rr < 8; ++rr) {
      float x = Pg[(size_t)(i0 + 8*w + rr) * LL + j0 + col];
      pL[8*w + rr][col + 1] = __expf(x - Mr[rr]) * iSr[rr];
    }
    if (tid < 32) {
      pL[tid][0] = lhalo[tid];
      int j = j0 + 64;
      pL[tid][65] = (j < LL) ? __expf(Pg[(size_t)(i0 + tid) * LL + j] - Mrow[tid]) * invS[tid] : 0.f;
    }
    {
      const short* src = &Vt[(size_t)vd * LL + j0 + vq * 16];
      float4 v0 = *(const float4*)(src);
      float4 v1 = *(const float4*)(src + 8);
      *(float4*)&Vsm[vd * 72 + vq * 16]     = v0;
      *(float4*)&Vsm[vd * 72 + vq * 16 + 8] = v1;
    }
    __syncthreads();

    // phase 2: 3-tap pool, write pooled in place, build bf16 A tile, save left halo
    #pragma unroll
    for (int rr = 0; rr < 8; ++rr) {
      int row = 8*w + rr;
      float p = (pL[row][col] + pL[row][col + 1] + pL[row][col + 2]) * (1.0f/3.0f);
      Pg[(size_t)(i0 + row) * LL + j0 + col] = p;
      Asm[row * 72 + col] = f2bf(p);
    }
    if (tid < 32) lhalo[tid] = pL[tid][64];
    __syncthreads();

    // phase 3: MFMA accumulate
    #pragma unroll
    for (int ch = 0; ch < 2; ++ch) {
      const int ka = ((lane >> 4) << 3) + ch * 32;
      bf16x8 af = *(const bf16x8*)&Asm[(wr * 16 + (lane & 15)) * 72 + ka];
      #pragma unroll
      for (int t = 0; t < 2; ++t) {
        bf16x8 bfv = *(const bf16x8*)&Vsm[((wd * 2 + t) * 16 + (lane & 15)) * 72 + ka];
        acc[t] = __builtin_amdgcn_mfma_f32_16x16x32_bf16(af, bfv, acc[t], 0, 0, 0);
      }
    }
    __syncthreads();
  }

  const int quad = lane >> 4, colg = lane & 15;
  #pragma unroll
  for (int t = 0; t < 2; ++t)
    #pragma unroll
    for (int r = 0; r < 4; ++r) {
      int i = i0 + wr * 16 + quad * 4 + r;
      int d = (wd * 2 + t) * 16 + colg;
      outh[((size_t)b * LL + i) * 512 + h * 64 + d] = acc[t][r];
    }
}

// ---------------- K5: fc = out_h @ w_fc^T  (bf16 MFMA, stride-72 LDS) ----------------
__global__ __launch_bounds__(256) void k_fc(
    const float* __restrict__ outh, const float* __restrict__ wfc, float* __restrict__ fcout)
{
  const int n0 = blockIdx.x * 64;
  const int m0 = blockIdx.y * 64;
  __shared__ short Asm[64 * 72];
  __shared__ short Bsm[64 * 72];
  const int tid = threadIdx.x;
  const int lane = tid & 63, w = tid >> 6;

  f32x4 acc[4];
  #pragma unroll
  for (int t = 0; t < 4; ++t) { acc[t][0]=0.f; acc[t][1]=0.f; acc[t][2]=0.f; acc[t][3]=0.f; }

  const int sr = tid >> 6, sc = tid & 63;     // lane = k-column
  for (int k0 = 0; k0 < 512; k0 += 64) {
    #pragma unroll
    for (int it = 0; it < 16; ++it) {
      int r = it * 4 + sr;
      Asm[r*72 + sc] = f2bf(outh[(size_t)(m0 + r) * 512 + k0 + sc]);
      Bsm[r*72 + sc] = f2bf(wfc [(size_t)(n0 + r) * 512 + k0 + sc]);
    }
    __syncthreads();
    #pragma unroll
    for (int ch = 0; ch < 2; ++ch) {
      const int ka = ((lane >> 4) << 3) + ch * 32;
      bf16x8 af = *(const bf16x8*)&Asm[(w * 16 + (lane & 15)) * 72 + ka];
      #pragma unroll
      for (int t = 0; t < 4; ++t) {
        bf16x8 bfv = *(const bf16x8*)&Bsm[(t * 16 + (lane & 15)) * 72 + ka];
        acc[t] = __builtin_amdgcn_mfma_f32_16x16x32_bf16(af, bfv, acc[t], 0, 0, 0);
      }
    }
    __syncthreads();
  }
  const int q4 = lane >> 4, colg = lane & 15;
  #pragma unroll
  for (int t = 0; t < 4; ++t)
    #pragma unroll
    for (int r = 0; r < 4; ++r) {
      int m = m0 + w * 16 + q4 * 4 + r;
      fcout[(size_t)m * 512 + n0 + t * 16 + colg] = acc[t][r];
    }
}

// ---------------- K6: residual + LayerNorm ----------------
__global__ __launch_bounds__(256) void k_ln(
    const float* __restrict__ fcout, const float* __restrict__ resid,
    const float* __restrict__ gamma, const float* __restrict__ beta,
    float* __restrict__ out)
{
  const size_t row = blockIdx.x;
  const int tid = threadIdx.x;
  __shared__ float red[256];

  float x0 = fcout[row * 512 + tid]       + resid[row * 512 + tid];
  float x1 = fcout[row * 512 + 256 + tid] + resid[row * 512 + 256 + tid];

  red[tid] = x0 + x1; __syncthreads();
  for (int off = 128; off > 0; off >>= 1) {
    if (tid < off) red[tid] += red[tid + off];
    __syncthreads();
  }
  const float mu = red[0] * (1.0f / 512.0f); __syncthreads();

  float d0 = x0 - mu, d1 = x1 - mu;
  red[tid] = d0 * d0 + d1 * d1; __syncthreads();
  for (int off = 128; off > 0; off >>= 1) {
    if (tid < off) red[tid] += red[tid + off];
    __syncthreads();
  }
  const float var = red[0] * (1.0f / 512.0f);
  const float rstd = 1.0f / sqrtf(var + 1e-6f);

  out[row * 512 + tid]       = d0 * rstd * gamma[tid]       + beta[tid];
  out[row * 512 + 256 + tid] = d1 * rstd * gamma[tid + 256] + beta[tid + 256];
}

// ---------------- launch ----------------
extern "C" void kernel_launch(void* const* d_in, const int* in_sizes, int n_in,
                              void* d_out, int out_size, void* d_ws, size_t ws_size,
                              hipStream_t stream)
{
  const float* q     = (const float*)d_in[0];
  const float* k     = (const float*)d_in[1];
  const float* v     = (const float*)d_in[2];
  const float* wq    = (const float*)d_in[3];
  const float* wk    = (const float*)d_in[4];
  const float* wv    = (const float*)d_in[5];
  const float* wfc   = (const float*)d_in[6];
  const float* gamma = (const float*)d_in[7];
  const float* beta  = (const float*)d_in[8];

  float* out    = (float*)d_out;
  float* pooled = out + OUT0;            // output 1; doubles as logits scratch

  float* wsf      = (float*)d_ws;        // 32 MB total
  float* qh       = wsf;                 // 8 MB (dead after k_qk -> rowstats)
  float* kh       = wsf + QH_ELEMS;      // 8 MB (dead after k_qk -> fcout)
  short* vt       = (short*)(wsf + 2 * QH_ELEMS);  // 4 MB bf16, V^T per head
  float* stats    = wsf + 3 * QH_ELEMS;  // 8 MB (dead after k_rowstats -> outh)
  float* outh     = wsf + 3 * QH_ELEMS;
  float* rowstats = qh;                  // 256 KB
  float* fcout    = kh;

  k_proj      <<<dim3(24, 64),     256, 0, stream>>>(q, k, v, wq, wk, wv, qh, kh, vt);
  k_qk        <<<dim3(32, 32, 16), 256, 0, stream>>>(qh, kh, pooled, stats);
  k_rowstats  <<<dim3(128),        256, 0, stream>>>(stats, rowstats);
  k_sm_pool_pv<<<dim3(64, 16),     256, 0, stream>>>(pooled, rowstats, vt, outh);
  k_fc        <<<dim3(8, 64),      256, 0, stream>>>(outh, wfc, fcout);
  k_ln        <<<dim3(4096),       256, 0, stream>>>(fcout, q, gamma, beta, out);
}

// Round 4
// 702.054 us; speedup vs baseline: 1.0757x; 1.0757x over previous
//
#include <hip/hip_runtime.h>
#include <cstddef>
#include <cstdint>

// ---------------- problem constants ----------------
#define ALPHA_C 7.7550531393693407f   // -log(0.001/7*3)
constexpr int BB = 2;      // batch
constexpr int LL = 2048;   // seq len
constexpr int HH = 8;      // heads
constexpr size_t OUT0  = (size_t)BB * LL * 512;          // output 0 floats
constexpr size_t PLANE = (size_t)BB * HH * LL * 64;      // elems per head-major plane

typedef __attribute__((ext_vector_type(8))) short bf16x8;
typedef __attribute__((ext_vector_type(4))) short short4v;
typedef __attribute__((ext_vector_type(4))) float f32x4;

__device__ inline short f2bf(float x) {
  union { float f; unsigned u; } un; un.f = x;
  unsigned r = un.u + 0x7fffu + ((un.u >> 16) & 1u);   // RNE
  return (short)(r >> 16);
}
__device__ inline float bf2f(short s) {
  union { unsigned u; float f; } un; un.u = ((unsigned)(unsigned short)s) << 16;
  return un.f;
}
// 3-way bf16 split: x ~= h + m + l (~24 mantissa bits)
__device__ inline void split3(float x, short& h, short& m, short& l) {
  h = f2bf(x); float r = x - bf2f(h);
  m = f2bf(r); float r2 = r - bf2f(m);
  l = f2bf(r2);
}

// ---------------- K1: fused QKV projection (fp32 SGEMM) ----------------
// grid (24, 64). sel 0/1 (Q/K): epilogue split3 -> 3 bf16 planes [bh][l][64].
// sel 2 (V): bf16 transposed vt[bh][d][l].
__global__ __launch_bounds__(256) void k_proj(
    const float* __restrict__ q, const float* __restrict__ k, const float* __restrict__ v,
    const float* __restrict__ wq, const float* __restrict__ wk, const float* __restrict__ wv,
    short* __restrict__ qs, short* __restrict__ ks, short* __restrict__ vt)
{
  const int bx  = blockIdx.x;
  const int sel = bx >> 3;                 // 0=q,1=k,2=v
  const int n0  = (bx & 7) * 64;
  const int m0  = blockIdx.y * 64;
  const float* X = sel == 0 ? q  : (sel == 1 ? k  : v);
  const float* W = sel == 0 ? wq : (sel == 1 ? wk : wv);

  __shared__ float As[32][68];
  __shared__ float Bs[32][68];
  const int tid = threadIdx.x;
  const int tr = tid >> 4, tc = tid & 15;
  const int lm = tid >> 2, lk0 = tid & 3;

  float acc[4][4] = {};
  for (int k0 = 0; k0 < 512; k0 += 32) {
    #pragma unroll
    for (int it = 0; it < 2; ++it) {
      int kv = lk0 + 4 * it;
      float4 a = *(const float4*)&X[(size_t)(m0 + lm) * 512 + k0 + kv * 4];
      As[kv*4+0][lm] = a.x; As[kv*4+1][lm] = a.y; As[kv*4+2][lm] = a.z; As[kv*4+3][lm] = a.w;
      float4 b = *(const float4*)&W[(size_t)(n0 + lm) * 512 + k0 + kv * 4];
      Bs[kv*4+0][lm] = b.x; Bs[kv*4+1][lm] = b.y; Bs[kv*4+2][lm] = b.z; Bs[kv*4+3][lm] = b.w;
    }
    __syncthreads();
    #pragma unroll 8
    for (int kk = 0; kk < 32; ++kk) {
      float4 av = *(const float4*)&As[kk][tr * 4];
      float4 bv = *(const float4*)&Bs[kk][tc * 4];
      acc[0][0] += av.x*bv.x; acc[0][1] += av.x*bv.y; acc[0][2] += av.x*bv.z; acc[0][3] += av.x*bv.w;
      acc[1][0] += av.y*bv.x; acc[1][1] += av.y*bv.y; acc[1][2] += av.y*bv.z; acc[1][3] += av.y*bv.w;
      acc[2][0] += av.z*bv.x; acc[2][1] += av.z*bv.y; acc[2][2] += av.z*bv.z; acc[2][3] += av.z*bv.w;
      acc[3][0] += av.w*bv.x; acc[3][1] += av.w*bv.y; acc[3][2] += av.w*bv.z; acc[3][3] += av.w*bv.w;
    }
    __syncthreads();
  }

  if (sel < 2) {
    short* Y = sel == 0 ? qs : ks;
    const int e = n0 + tc * 4;
    const int h = e >> 6, dk = e & 63;
    #pragma unroll
    for (int r = 0; r < 4; ++r) {
      int m = m0 + tr * 4 + r;
      int b = m >> 11, l = m & 2047;
      size_t base = ((size_t)(b * HH + h) * LL + l) * 64 + dk;
      short4v sh, sm, sl;
      #pragma unroll
      for (int c = 0; c < 4; ++c) {
        short hh, mm, ll; split3(acc[r][c], hh, mm, ll);
        sh[c] = hh; sm[c] = mm; sl[c] = ll;
      }
      *(short4v*)&Y[base]             = sh;
      *(short4v*)&Y[PLANE + base]     = sm;
      *(short4v*)&Y[2 * PLANE + base] = sl;
    }
  } else {
    const int b  = m0 >> 11;
    const int l0 = (m0 & 2047) + tr * 4;
    #pragma unroll
    for (int c = 0; c < 4; ++c) {
      int e = n0 + tc * 4 + c, h = e >> 6, dk = e & 63;
      short4v s;
      s[0] = f2bf(acc[0][c]); s[1] = f2bf(acc[1][c]);
      s[2] = f2bf(acc[2][c]); s[3] = f2bf(acc[3][c]);
      *(short4v*)&vt[(((size_t)b * HH + h) * 64 + dk) * LL + l0] = s;
    }
  }
}

// ---------------- K2 (pass A): flash stats — rowwise (M, S), no logit store ------
// grid (32 i-tiles of 64 rows, 16 bh), 256 thr. 6-term split MFMA, online stats.
__global__ __launch_bounds__(256) void k_stats(
    const short* __restrict__ qs, const short* __restrict__ ks,
    float* __restrict__ rowstats)
{
  const int i0 = blockIdx.x * 64;
  const int bh = blockIdx.y;
  __shared__ short Qs[3][64 * 72];
  __shared__ short Ks[3][64 * 72];
  const int tid = threadIdx.x;
  const int lane = tid & 63, w = tid >> 6;
  const int quad = lane >> 4, colg = lane & 15, l15 = lane & 15;

  // stage Q once: thread -> (row, 4-col chunk)
  const int sr = tid >> 4, sc4 = (tid & 15) * 4;
  #pragma unroll
  for (int p = 0; p < 3; ++p) {
    const short* plane = qs + (size_t)p * PLANE + ((size_t)bh * LL + i0) * 64;
    #pragma unroll
    for (int it = 0; it < 4; ++it) {
      int r = it * 16 + sr;
      *(short4v*)&Qs[p][r * 72 + sc4] = *(const short4v*)&plane[(size_t)r * 64 + sc4];
    }
  }

  float M[4], S[4];
  #pragma unroll
  for (int r = 0; r < 4; ++r) { M[r] = -3.0e38f; S[r] = 0.f; }

  for (int jt = 0; jt < 32; ++jt) {
    const int j0 = jt * 64;
    __syncthreads();   // protect Ks from previous iteration's MFMA reads
    #pragma unroll
    for (int p = 0; p < 3; ++p) {
      const short* plane = ks + (size_t)p * PLANE + ((size_t)bh * LL + j0) * 64;
      #pragma unroll
      for (int it = 0; it < 4; ++it) {
        int r = it * 16 + sr;
        *(short4v*)&Ks[p][r * 72 + sc4] = *(const short4v*)&plane[(size_t)r * 64 + sc4];
      }
    }
    __syncthreads();

    f32x4 acc[4];
    #pragma unroll
    for (int t = 0; t < 4; ++t) { acc[t][0]=0.f; acc[t][1]=0.f; acc[t][2]=0.f; acc[t][3]=0.f; }
    #pragma unroll
    for (int ch = 0; ch < 2; ++ch) {
      const int ka = (quad << 3) + ch * 32;
      const int ar = (w * 16 + l15) * 72 + ka;
      bf16x8 ah = *(const bf16x8*)&Qs[0][ar];
      bf16x8 am = *(const bf16x8*)&Qs[1][ar];
      bf16x8 al = *(const bf16x8*)&Qs[2][ar];
      #pragma unroll
      for (int t = 0; t < 4; ++t) {
        const int br = (t * 16 + l15) * 72 + ka;
        bf16x8 bh_ = *(const bf16x8*)&Ks[0][br];
        bf16x8 bm_ = *(const bf16x8*)&Ks[1][br];
        bf16x8 bl_ = *(const bf16x8*)&Ks[2][br];
        acc[t] = __builtin_amdgcn_mfma_f32_16x16x32_bf16(ah, bh_, acc[t], 0, 0, 0);
        acc[t] = __builtin_amdgcn_mfma_f32_16x16x32_bf16(ah, bm_, acc[t], 0, 0, 0);
        acc[t] = __builtin_amdgcn_mfma_f32_16x16x32_bf16(am, bh_, acc[t], 0, 0, 0);
        acc[t] = __builtin_amdgcn_mfma_f32_16x16x32_bf16(ah, bl_, acc[t], 0, 0, 0);
        acc[t] = __builtin_amdgcn_mfma_f32_16x16x32_bf16(al, bh_, acc[t], 0, 0, 0);
        acc[t] = __builtin_amdgcn_mfma_f32_16x16x32_bf16(am, bm_, acc[t], 0, 0, 0);
      }
    }

    // per-row online stats over this 64-col tile
    #pragma unroll
    for (int r = 0; r < 4; ++r) {
      const int irow = i0 + w * 16 + quad * 4 + r;
      float e0 = -ALPHA_C * (float)(j0 +  0 + colg - irow) * (acc[0][r] * 0.125f);
      float e1 = -ALPHA_C * (float)(j0 + 16 + colg - irow) * (acc[1][r] * 0.125f);
      float e2 = -ALPHA_C * (float)(j0 + 32 + colg - irow) * (acc[2][r] * 0.125f);
      float e3 = -ALPHA_C * (float)(j0 + 48 + colg - irow) * (acc[3][r] * 0.125f);
      float mx = fmaxf(fmaxf(e0, e1), fmaxf(e2, e3));
      #pragma unroll
      for (int d = 1; d < 16; d <<= 1) mx = fmaxf(mx, __shfl_xor(mx, d));
      float s = __expf(e0 - mx) + __expf(e1 - mx) + __expf(e2 - mx) + __expf(e3 - mx);
      #pragma unroll
      for (int d = 1; d < 16; d <<= 1) s += __shfl_xor(s, d);
      float nM = fmaxf(M[r], mx);
      S[r] = S[r] * __expf(M[r] - nM) + s * __expf(mx - nM);
      M[r] = nM;
    }
  }

  if (colg == 0) {
    #pragma unroll
    for (int r = 0; r < 4; ++r) {
      int irow = i0 + w * 16 + quad * 4 + r;
      size_t idx = ((size_t)bh * LL + irow) * 2;
      rowstats[idx] = M[r]; rowstats[idx + 1] = S[r];
    }
  }
}

// ---------------- K3 (pass B): recompute QK -> softmax -> pool -> write pooled + PV ----
// grid (64 i-tiles of 32 rows, 16 bh), 256 thr. Pipelined pooling (tile jt-1 pooled
// once tile jt's first column is known). Single write of pooled; PV accumulated.
__global__ __launch_bounds__(256) void k_pool_pv(
    const short* __restrict__ qs, const short* __restrict__ ks,
    const short* __restrict__ vt, const float* __restrict__ rowstats,
    float* __restrict__ pooled, float* __restrict__ outh)
{
  const int i0 = blockIdx.x * 32;
  const int bh = blockIdx.y;
  const int b = bh >> 3, h = bh & 7;
  float*       Pg = pooled + (size_t)bh * LL * LL;
  const short* Vt = vt + (size_t)bh * 64 * LL;

  __shared__ short Qs[3][32 * 72];
  __shared__ short Ks[3][64 * 72];
  __shared__ short Vsm[64 * 72];
  __shared__ float Pbuf[2][32 * 66];
  __shared__ short Asm[32 * 72];
  __shared__ float Mrow[32], invSr[32], lhalo[32];

  const int tid = threadIdx.x;
  const int lane = tid & 63, w = tid >> 6;
  const int quad = lane >> 4, colg = lane & 15, l15 = lane & 15;
  const int rg = w & 1, cg = w >> 1;         // QK/PV wave tiling: rows 16*rg, cols 32*cg

  // stage Q (32 rows) once
  const int sr = tid >> 4, sc4 = (tid & 15) * 4;
  #pragma unroll
  for (int p = 0; p < 3; ++p) {
    const short* plane = qs + (size_t)p * PLANE + ((size_t)bh * LL + i0) * 64;
    #pragma unroll
    for (int it = 0; it < 2; ++it) {
      int r = it * 16 + sr;
      *(short4v*)&Qs[p][r * 72 + sc4] = *(const short4v*)&plane[(size_t)r * 64 + sc4];
    }
  }
  if (tid < 32) {
    float2 ms = *(const float2*)&rowstats[((size_t)bh * LL + i0 + tid) * 2];
    Mrow[tid] = ms.x; invSr[tid] = 1.0f / ms.y; lhalo[tid] = 0.f;
  }

  f32x4 pv[2];
  pv[0][0]=0.f;pv[0][1]=0.f;pv[0][2]=0.f;pv[0][3]=0.f;
  pv[1][0]=0.f;pv[1][1]=0.f;pv[1][2]=0.f;pv[1][3]=0.f;

  const int vd = tid >> 2, vq = tid & 3;     // V staging mapping

  for (int jt = 0; jt <= 32; ++jt) {
    // ---- phase 0: stage K tile jt; stage V tile jt-1 ----
    if (jt < 32) {
      const int j0 = jt * 64;
      #pragma unroll
      for (int p = 0; p < 3; ++p) {
        const short* plane = ks + (size_t)p * PLANE + ((size_t)bh * LL + j0) * 64;
        #pragma unroll
        for (int it = 0; it < 4; ++it) {
          int r = it * 16 + sr;
          *(short4v*)&Ks[p][r * 72 + sc4] = *(const short4v*)&plane[(size_t)r * 64 + sc4];
        }
      }
    }
    if (jt >= 1) {
      const short* src = &Vt[(size_t)vd * LL + (jt - 1) * 64 + vq * 16];
      float4 v0 = *(const float4*)(src);
      float4 v1 = *(const float4*)(src + 8);
      *(float4*)&Vsm[vd * 72 + vq * 16]     = v0;
      *(float4*)&Vsm[vd * 72 + vq * 16 + 8] = v1;
    }
    __syncthreads();

    // ---- phase 1: QK -> p into Pbuf[jt&1] ----
    if (jt < 32) {
      const int j0 = jt * 64;
      f32x4 acc[2];
      acc[0][0]=0.f;acc[0][1]=0.f;acc[0][2]=0.f;acc[0][3]=0.f;
      acc[1][0]=0.f;acc[1][1]=0.f;acc[1][2]=0.f;acc[1][3]=0.f;
      #pragma unroll
      for (int ch = 0; ch < 2; ++ch) {
        const int ka = (quad << 3) + ch * 32;
        const int ar = (rg * 16 + l15) * 72 + ka;
        bf16x8 ah = *(const bf16x8*)&Qs[0][ar];
        bf16x8 am = *(const bf16x8*)&Qs[1][ar];
        bf16x8 al = *(const bf16x8*)&Qs[2][ar];
        #pragma unroll
        for (int t = 0; t < 2; ++t) {
          const int br = ((cg * 2 + t) * 16 + l15) * 72 + ka;
          bf16x8 bh_ = *(const bf16x8*)&Ks[0][br];
          bf16x8 bm_ = *(const bf16x8*)&Ks[1][br];
          bf16x8 bl_ = *(const bf16x8*)&Ks[2][br];
          acc[t] = __builtin_amdgcn_mfma_f32_16x16x32_bf16(ah, bh_, acc[t], 0, 0, 0);
          acc[t] = __builtin_amdgcn_mfma_f32_16x16x32_bf16(ah, bm_, acc[t], 0, 0, 0);
          acc[t] = __builtin_amdgcn_mfma_f32_16x16x32_bf16(am, bh_, acc[t], 0, 0, 0);
          acc[t] = __builtin_amdgcn_mfma_f32_16x16x32_bf16(ah, bl_, acc[t], 0, 0, 0);
          acc[t] = __builtin_amdgcn_mfma_f32_16x16x32_bf16(al, bh_, acc[t], 0, 0, 0);
          acc[t] = __builtin_amdgcn_mfma_f32_16x16x32_bf16(am, bm_, acc[t], 0, 0, 0);
        }
      }
      float* Pb = Pbuf[jt & 1];
      #pragma unroll
      for (int r = 0; r < 4; ++r) {
        const int row = rg * 16 + quad * 4 + r;
        const int irow = i0 + row;
        const float Mr = Mrow[row], iS = invSr[row];
        #pragma unroll
        for (int t = 0; t < 2; ++t) {
          int jl = (cg * 2 + t) * 16 + colg;
          float e = -ALPHA_C * (float)(j0 + jl - irow) * (acc[t][r] * 0.125f);
          Pb[row * 66 + jl] = __expf(e - Mr) * iS;
        }
      }
    }
    __syncthreads();

    // ---- phase 2: pool tile jt-1, write pooled, build Asm ----
    if (jt >= 1) {
      const float* Pp = Pbuf[(jt & 1) ^ 1];
      const float* Pc = Pbuf[jt & 1];
      const int col = lane;
      #pragma unroll
      for (int rr = 0; rr < 8; ++rr) {
        const int row = 8 * w + rr;
        float mid = Pp[row * 66 + col];
        float lft = (col == 0)  ? lhalo[row] : Pp[row * 66 + col - 1];
        float rgt = (col == 63) ? ((jt < 32) ? Pc[row * 66] : 0.f)
                                : Pp[row * 66 + col + 1];
        float pl = (lft + mid + rgt) * (1.0f / 3.0f);
        Pg[(size_t)(i0 + row) * LL + (jt - 1) * 64 + col] = pl;
        Asm[row * 72 + col] = f2bf(pl);
        if (col == 63) lhalo[row] = mid;
      }
    }
    __syncthreads();

    // ---- phase 3: PV MFMA for tile jt-1 ----
    if (jt >= 1) {
      #pragma unroll
      for (int ch = 0; ch < 2; ++ch) {
        const int ka = (quad << 3) + ch * 32;
        bf16x8 af = *(const bf16x8*)&Asm[(rg * 16 + l15) * 72 + ka];
        #pragma unroll
        for (int t = 0; t < 2; ++t) {
          bf16x8 bfv = *(const bf16x8*)&Vsm[((cg * 2 + t) * 16 + l15) * 72 + ka];
          pv[t] = __builtin_amdgcn_mfma_f32_16x16x32_bf16(af, bfv, pv[t], 0, 0, 0);
        }
      }
    }
    __syncthreads();
  }

  #pragma unroll
  for (int t = 0; t < 2; ++t)
    #pragma unroll
    for (int r = 0; r < 4; ++r) {
      int i = i0 + rg * 16 + quad * 4 + r;
      int d = cg * 32 + t * 16 + colg;
      outh[((size_t)b * LL + i) * 512 + h * 64 + d] = pv[t][r];
    }
}

// ---------------- K4: fc = out_h @ w_fc^T  (bf16 MFMA, stride-72 LDS) ----------------
__global__ __launch_bounds__(256) void k_fc(
    const float* __restrict__ outh, const float* __restrict__ wfc, float* __restrict__ fcout)
{
  const int n0 = blockIdx.x * 64;
  const int m0 = blockIdx.y * 64;
  __shared__ short Asm[64 * 72];
  __shared__ short Bsm[64 * 72];
  const int tid = threadIdx.x;
  const int lane = tid & 63, w = tid >> 6;

  f32x4 acc[4];
  #pragma unroll
  for (int t = 0; t < 4; ++t) { acc[t][0]=0.f; acc[t][1]=0.f; acc[t][2]=0.f; acc[t][3]=0.f; }

  const int sr = tid >> 6, sc = tid & 63;
  for (int k0 = 0; k0 < 512; k0 += 64) {
    #pragma unroll
    for (int it = 0; it < 16; ++it) {
      int r = it * 4 + sr;
      Asm[r*72 + sc] = f2bf(outh[(size_t)(m0 + r) * 512 + k0 + sc]);
      Bsm[r*72 + sc] = f2bf(wfc [(size_t)(n0 + r) * 512 + k0 + sc]);
    }
    __syncthreads();
    #pragma unroll
    for (int ch = 0; ch < 2; ++ch) {
      const int ka = ((lane >> 4) << 3) + ch * 32;
      bf16x8 af = *(const bf16x8*)&Asm[(w * 16 + (lane & 15)) * 72 + ka];
      #pragma unroll
      for (int t = 0; t < 4; ++t) {
        bf16x8 bfv = *(const bf16x8*)&Bsm[(t * 16 + (lane & 15)) * 72 + ka];
        acc[t] = __builtin_amdgcn_mfma_f32_16x16x32_bf16(af, bfv, acc[t], 0, 0, 0);
      }
    }
    __syncthreads();
  }
  const int q4 = lane >> 4, colg = lane & 15;
  #pragma unroll
  for (int t = 0; t < 4; ++t)
    #pragma unroll
    for (int r = 0; r < 4; ++r) {
      int m = m0 + w * 16 + q4 * 4 + r;
      fcout[(size_t)m * 512 + n0 + t * 16 + colg] = acc[t][r];
    }
}

// ---------------- K5: residual + LayerNorm ----------------
__global__ __launch_bounds__(256) void k_ln(
    const float* __restrict__ fcout, const float* __restrict__ resid,
    const float* __restrict__ gamma, const float* __restrict__ beta,
    float* __restrict__ out)
{
  const size_t row = blockIdx.x;
  const int tid = threadIdx.x;
  __shared__ float red[256];

  float x0 = fcout[row * 512 + tid]       + resid[row * 512 + tid];
  float x1 = fcout[row * 512 + 256 + tid] + resid[row * 512 + 256 + tid];

  red[tid] = x0 + x1; __syncthreads();
  for (int off = 128; off > 0; off >>= 1) {
    if (tid < off) red[tid] += red[tid + off];
    __syncthreads();
  }
  const float mu = red[0] * (1.0f / 512.0f); __syncthreads();

  float d0 = x0 - mu, d1 = x1 - mu;
  red[tid] = d0 * d0 + d1 * d1; __syncthreads();
  for (int off = 128; off > 0; off >>= 1) {
    if (tid < off) red[tid] += red[tid + off];
    __syncthreads();
  }
  const float var = red[0] * (1.0f / 512.0f);
  const float rstd = 1.0f / sqrtf(var + 1e-6f);

  out[row * 512 + tid]       = d0 * rstd * gamma[tid]       + beta[tid];
  out[row * 512 + 256 + tid] = d1 * rstd * gamma[tid + 256] + beta[tid + 256];
}

// ---------------- launch ----------------
extern "C" void kernel_launch(void* const* d_in, const int* in_sizes, int n_in,
                              void* d_out, int out_size, void* d_ws, size_t ws_size,
                              hipStream_t stream)
{
  const float* q     = (const float*)d_in[0];
  const float* k     = (const float*)d_in[1];
  const float* v     = (const float*)d_in[2];
  const float* wq    = (const float*)d_in[3];
  const float* wk    = (const float*)d_in[4];
  const float* wv    = (const float*)d_in[5];
  const float* wfc   = (const float*)d_in[6];
  const float* gamma = (const float*)d_in[7];
  const float* beta  = (const float*)d_in[8];

  float* out    = (float*)d_out;
  float* pooled = out + OUT0;

  // workspace layout (ws is ~800 MB; we use ~44 MB)
  short* qs       = (short*)d_ws;                    // 3 planes bf16
  short* ks       = qs + 3 * PLANE;                  // 3 planes bf16
  short* vt       = ks + 3 * PLANE;                  // 1 plane bf16 (V^T)
  float* outh     = (float*)(vt + PLANE);            // 8 MB
  float* rowstats = outh + OUT0;                     // 256 KB
  float* fcout    = rowstats + 2 * (size_t)BB * HH * LL;  // 8 MB

  k_proj   <<<dim3(24, 64), 256, 0, stream>>>(q, k, v, wq, wk, wv, qs, ks, vt);
  k_stats  <<<dim3(32, 16), 256, 0, stream>>>(qs, ks, rowstats);
  k_pool_pv<<<dim3(64, 16), 256, 0, stream>>>(qs, ks, vt, rowstats, pooled, outh);
  k_fc     <<<dim3(8, 64),  256, 0, stream>>>(outh, wfc, fcout);
  k_ln     <<<dim3(4096),   256, 0, stream>>>(fcout, q, gamma, beta, out);
}